// Round 11
// baseline (264.132 us; speedup 1.0000x reference)
//
#include <hip/hip_runtime.h>
#include <hip/hip_bf16.h>
#include <math.h>

#define DD 8192     // sketch dimension d
#define CC 768      // channels
#define SS 145      // sequence length
#define BB 32       // batch
#define SN 64       // sensor dim
#define SROWS 160   // padded s rows (10 tiles of 16)

// ---- kD geometry ----
#define TN 64            // e-cols per block
#define NET (CC/TN)      // 12 e-tiles
#define CK 64            // c per chunk
#define NCHK (CC/CK)     // 12 chunks
#define LTW 72           // Lt row stride in bf16 units (144 B = 9x16B: aligned, conflict-free)
#define NTD 512          // 8 waves
#define NWG (NET*BB*3)   // 1152 blocks

// ---- kZ geometry ----
#define ZT 512           // threads
#define NSL 16           // d-slices per b -> 512 blocks

typedef __attribute__((ext_vector_type(8))) short short8;   // 8 bf16 (4 VGPR)
typedef __attribute__((ext_vector_type(4))) float f32x4;    // MFMA acc

// ---------------------------------------------------------------------------
// kS: per-b sketch build. u[b,c]=b_sen[c]+sensor·Wsen[c,:];
// CTG[b][c]=(u1, s1, bits(h1c), 0); P2G[b][t]=(S2u_b[t], S2s[t]).
// ---------------------------------------------------------------------------
__global__ __launch_bounds__(512) void kS(
    const float* __restrict__ sensor, const float* __restrict__ Wsen,
    const float* __restrict__ bsen,
    const int* __restrict__ h1, const int* __restrict__ h2,
    const int* __restrict__ s1, const int* __restrict__ s2,
    float4* __restrict__ CTG, float2* __restrict__ P2G)
{
    __shared__ float2 P2l[DD];        // 64 KB
    __shared__ float  sens[SN];
    const int b   = blockIdx.x;
    const int tid = threadIdx.x;

    if (tid < SN) sens[tid] = sensor[b*SN + tid];
    {
        float4* p4 = (float4*)P2l;
        #pragma unroll
        for (int i = 0; i < 8; ++i) p4[tid + i*512] = make_float4(0.f,0.f,0.f,0.f);
    }
    __syncthreads();

    for (int c = tid; c < CC; c += 512) {
        float u = bsen[c];
        const float4* w = (const float4*)(Wsen + (size_t)c*SN);
        #pragma unroll
        for (int n4 = 0; n4 < 16; ++n4) {
            float4 wv = w[n4];
            u += sens[4*n4+0]*wv.x + sens[4*n4+1]*wv.y
               + sens[4*n4+2]*wv.z + sens[4*n4+3]*wv.w;
        }
        float f1 = (float)s1[c], f2 = (float)s2[c];
        float4 ct;
        ct.x = u * f1; ct.y = f1; ct.z = __int_as_float(h1[c]); ct.w = 0.f;
        CTG[(size_t)b*CC + c] = ct;
        int t = h2[c];
        unsafeAtomicAdd(&P2l[t].x, u * f2);
        unsafeAtomicAdd(&P2l[t].y, f2);
    }
    __syncthreads();

    {
        const float4* p4 = (const float4*)P2l;
        float4* dst = (float4*)(P2G + (size_t)b*DD);
        #pragma unroll
        for (int i = 0; i < 8; ++i) dst[tid + i*512] = p4[tid + i*512];
    }
}

// ---------------------------------------------------------------------------
// kZ: gather-free Z build via shifted-sketch sums (unchanged).
//   Zuu_b[d]=sum_c u1[c]*S2u[(d-h1c)], Zcr_b[d]=sum u1*S2s+s1*S2u,
//   Z11[d]=sum s1*S2s (b==0 writes). Writes bf16 Zsb directly.
// ---------------------------------------------------------------------------
__global__ __launch_bounds__(ZT) void kZ(
    const float4* __restrict__ CTG, const float2* __restrict__ P2G,
    __hip_bfloat16* __restrict__ Zsb)
{
    __shared__ float2 P2l[DD];        // 64 KB -> 2 blocks/CU

    const int bid = blockIdx.x;
    const int wg  = (bid & 7)*(BB*NSL/8) + (bid >> 3);
    const int b   = wg >> 4;
    const int dsl = wg & (NSL-1);
    const int tid = threadIdx.x;

    {
        const float4* src = (const float4*)(P2G + (size_t)b*DD);
        float4* dst = (float4*)P2l;
        #pragma unroll
        for (int i = 0; i < 8; ++i) dst[tid + i*ZT] = src[tid + i*ZT];
    }
    __syncthreads();

    const int d = dsl*ZT + tid;
    const float4* ctp = CTG + (size_t)b*CC;
    float accU = 0.f, accC = 0.f, acc1 = 0.f;
    #pragma unroll 4
    for (int c = 0; c < CC; ++c) {
        float4 ct = ctp[c];                       // uniform -> s_load path
        int idx = (d - __float_as_int(ct.z)) & (DD-1);
        float2 p = P2l[idx];                      // conflict-free b64 gather
        accU = fmaf(ct.x, p.x, accU);
        accC = fmaf(ct.x, p.y, fmaf(ct.y, p.x, accC));
        acc1 = fmaf(ct.y, p.y, acc1);
    }

    Zsb[(size_t)b*DD + d]        = __float2bfloat16(accU);
    Zsb[(size_t)(BB + b)*DD + d] = __float2bfloat16(accC);
    if (b == 0) Zsb[(size_t)2*BB*DD + d] = __float2bfloat16(acc1);
}

// ---------------------------------------------------------------------------
// kA: precompute A1[b][sp][c] = bf16((E[b,sp,c]+tok1[c])*s1[c]), zero rows
// for sp>=SS. 7.9 MB, L2-resident for kD.
// ---------------------------------------------------------------------------
__global__ __launch_bounds__(384) void kA(
    const float* __restrict__ E, const float* __restrict__ tok,
    const int* __restrict__ s1, __hip_bfloat16* __restrict__ A1)
{
    const int b  = blockIdx.x;
    const int r0 = blockIdx.y * 16;
    const int p  = threadIdx.x;           // c-pair 0..383
    const int c  = 2*p;
    const float s1a = (float)s1[c], s1b = (float)s1[c+1];
    const float ta = tok[CC + c] * s1a, tb = tok[CC + c + 1] * s1b;
    #pragma unroll
    for (int rr = 0; rr < 16; ++rr) {
        int sp = r0 + rr;
        unsigned int word = 0;
        if (sp < SS) {
            float2 ev = *(const float2*)&E[((size_t)b*SS + sp)*CC + c];
            __hip_bfloat16 x0 = __float2bfloat16(ev.x*s1a + ta);
            __hip_bfloat16 x1 = __float2bfloat16(ev.y*s1b + tb);
            word = (unsigned int)*(unsigned short*)&x0
                 | ((unsigned int)*(unsigned short*)&x1 << 16);
        }
        *(unsigned int*)&A1[((size_t)b*SROWS + sp)*CC + c] = word;
    }
}

// ---------------------------------------------------------------------------
// kD: bf16 MFMA quadratic forms, minimum-LDS / max-occupancy variant.
// B-fragments are gathered IN-REGISTER from LDS Zm: lane (l15,l4) needs
// M[c,e] for 8 consecutive c and ONE e, so h2[e] is a lane-constant register
// and h1 comes from per-lane int4 loads of the L1-hot 3KB h1 array. No Mt
// buffer, no gather barrier. Lt staged per chunk from bf16 A1 (uint4 copies,
// T14 preload-early/write-late), 2 barriers per chunk.
// LDS = Zm 16K + Lt 23K = 39424 B -> 4 blocks/CU; launch_bounds(512,8)
// forces VGPR<=64 -> 32 waves/CU (core live state: acc 20 + pf 12 regs).
//   m=0: w2^2*Zuu[b]  m=1: w2*bb*Zcr[b]  m=2: bb^2*Z11.
// ---------------------------------------------------------------------------
__global__ __launch_bounds__(NTD, 8) void kD(
    const __hip_bfloat16* __restrict__ A1,
    const float* __restrict__ E, const float* __restrict__ tok,
    const int* __restrict__ h1, const int* __restrict__ h2,
    const int* __restrict__ s2,
    const float* __restrict__ Ws2, const float* __restrict__ bs2,
    const __hip_bfloat16* __restrict__ Zsb, float* __restrict__ Q)
{
    __shared__ __align__(16) unsigned short Zm[DD];          // 16384 B
    __shared__ __align__(16) unsigned short Lt[SROWS*LTW];   // 23040 B
    // total 39424 B -> 4 blocks/CU

    const int bid = blockIdx.x;
    const int wg  = (bid & 7)*(NWG/8) + (bid >> 3);
    const int b   = wg / (3*NET);
    const int r   = wg % (3*NET);
    const int m   = r / NET;
    const int et  = r % NET;
    const int tid = threadIdx.x;
    const int e0  = et * TN;

    // stage Zm (bf16, coalesced uint4 from L2-resident Zsb)
    {
        const uint4* src = (const uint4*)(Zsb +
            (size_t)((m == 0) ? b : (m == 1) ? (BB + b) : 2*BB) * DD);
        uint4* dst = (uint4*)Zm;
        #pragma unroll
        for (int i = 0; i < 2; ++i) dst[tid + i*NTD] = src[tid + i*NTD];
    }

    const int lane = tid & 63;
    const int w    = tid >> 6;        // wave 0..7
    const int eT   = w & 3;           // e-tile within block
    const int sB   = (w >> 2) * 5;    // first s-tile
    const int l15  = lane & 15;
    const int l4   = lane >> 4;

    const int   eg   = e0 + eT*16 + l15;   // this lane's e column
    const int   myh2 = h2[eg];             // lane-constant gather offset

    // Lt staging: 1280 uint4 over 512 threads (3 passes, last partial)
    uint4 pf[3];
#define PRELOAD(CKK) { \
    _Pragma("unroll") \
    for (int p = 0; p < 3; ++p) { \
        int i = tid + p*512; \
        if (i < 1280) { \
            int row = i >> 3, q = i & 7; \
            pf[p] = *(const uint4*)&A1[((size_t)b*SROWS + row)*CC \
                                       + (CKK)*CK + q*8]; \
        } } }
#define WRITE_A { \
    _Pragma("unroll") \
    for (int p = 0; p < 3; ++p) { \
        int i = tid + p*512; \
        if (i < 1280) { \
            int row = i >> 3, q = i & 7; \
            *(uint4*)&Lt[row*LTW + q*8] = pf[p]; \
        } } }

    f32x4 acc[5];
    #pragma unroll
    for (int t = 0; t < 5; ++t) acc[t] = (f32x4){0.f, 0.f, 0.f, 0.f};

    PRELOAD(0)
    WRITE_A
    __syncthreads();

    for (int ck = 0; ck < NCHK; ++ck) {
        if (ck + 1 < NCHK) PRELOAD(ck + 1)   // hides under MFMA + barrier

        #pragma unroll
        for (int kk = 0; kk < 2; ++kk) {
            // ---- in-register B-fragment gather ----
            const int cb = ck*CK + kk*32 + l4*8;
            const int4 ha = *(const int4*)&h1[cb];
            const int4 hb = *(const int4*)&h1[cb + 4];
            unsigned int g0 = Zm[(ha.x + myh2) & (DD-1)];
            unsigned int g1 = Zm[(ha.y + myh2) & (DD-1)];
            unsigned int g2 = Zm[(ha.z + myh2) & (DD-1)];
            unsigned int g3 = Zm[(ha.w + myh2) & (DD-1)];
            unsigned int g4 = Zm[(hb.x + myh2) & (DD-1)];
            unsigned int g5 = Zm[(hb.y + myh2) & (DD-1)];
            unsigned int g6 = Zm[(hb.z + myh2) & (DD-1)];
            unsigned int g7 = Zm[(hb.w + myh2) & (DD-1)];
            union { unsigned int u[4]; short8 s; } bf;
            bf.u[0] = g0 | (g1 << 16);
            bf.u[1] = g2 | (g3 << 16);
            bf.u[2] = g4 | (g5 << 16);
            bf.u[3] = g6 | (g7 << 16);

            const int kb = kk*32 + l4*8;
            #pragma unroll
            for (int t = 0; t < 5; ++t) {
                short8 afrag = *(const short8*)&Lt[((sB + t)*16 + l15)*LTW + kb];
                acc[t] = __builtin_amdgcn_mfma_f32_16x16x32_bf16(
                    afrag, bf.s, acc[t], 0, 0, 0);
            }
        }
        __syncthreads();

        if (ck + 1 < NCHK) {
            WRITE_A
            __syncthreads();
        }
    }
#undef PRELOAD
#undef WRITE_A

    // --- epilogue: q[s] = sum_e acc * a2[s,e]; reduce 16 e-lanes; scale; add ---
    const float s2e = (float)s2[eg];
    const float t2e = tok[CC + eg] * s2e;
    #pragma unroll
    for (int t = 0; t < 5; ++t) {
        #pragma unroll
        for (int rr = 0; rr < 4; ++rr) {
            int s = (sB + t)*16 + l4*4 + rr;
            float qv = 0.f;
            if (s < SS) {
                float a2v = E[((size_t)b*SS + s)*CC + eg] * s2e + t2e;
                qv = acc[t][rr] * a2v;
            }
            qv += __shfl_xor(qv, 1);
            qv += __shfl_xor(qv, 2);
            qv += __shfl_xor(qv, 4);
            qv += __shfl_xor(qv, 8);
            if (l15 == 0 && s < SS) {
                float w2v = Ws2[s], bbv = bs2[s];
                float sc  = (m == 0) ? w2v*w2v : (m == 1) ? w2v*bbv : bbv*bbv;
                unsafeAtomicAdd(&Q[b*SS + s], sc * qv);
            }
        }
    }
}

// ---------------------------------------------------------------------------
// kE: bp = sign(Q)*sqrt(|Q|+1e-5); L2-normalize over s; project W_out.
// ---------------------------------------------------------------------------
__global__ __launch_bounds__(256) void kE(
    const float* __restrict__ Q, const float* __restrict__ Wout,
    const float* __restrict__ bout, float* __restrict__ out)
{
    __shared__ float red[8];
    const int b = blockIdx.x, tid = threadIdx.x;
    float v = 0.f, w = 0.f;
    if (tid < SS) {
        float ip = Q[b*SS + tid];
        float sg = (ip > 0.f) ? 1.f : ((ip < 0.f) ? -1.f : 0.f);
        v = sg * sqrtf(fabsf(ip) + 1e-5f);
        w = v * Wout[tid];
    }
    float sq = v * v;
    #pragma unroll
    for (int off = 32; off > 0; off >>= 1) {
        sq += __shfl_down(sq, off, 64);
        w  += __shfl_down(w,  off, 64);
    }
    if ((tid & 63) == 0) { red[tid >> 6] = sq; red[4 + (tid >> 6)] = w; }
    __syncthreads();
    if (tid == 0) {
        float ssq  = red[0] + red[1] + red[2] + red[3];
        float sw   = red[4] + red[5] + red[6] + red[7];
        float norm = fmaxf(sqrtf(ssq), 1e-12f);
        out[b] = sw / norm + bout[0];
    }
}

// ---------------------------------------------------------------------------
extern "C" void kernel_launch(void* const* d_in, const int* in_sizes, int n_in,
                              void* d_out, int out_size, void* d_ws, size_t ws_size,
                              hipStream_t stream) {
    const float* sensor = (const float*)d_in[0];
    const float* E      = (const float*)d_in[1];
    const int*   h1     = (const int*)d_in[3];
    const int*   h2     = (const int*)d_in[4];
    const int*   s1     = (const int*)d_in[5];
    const int*   s2     = (const int*)d_in[6];
    const float* Wsen   = (const float*)d_in[8];
    const float* bsen   = (const float*)d_in[9];
    const float* Ws2    = (const float*)d_in[10];
    const float* bs2    = (const float*)d_in[11];
    const float* Wout   = (const float*)d_in[12];
    const float* bout   = (const float*)d_in[13];
    const float* tok    = (const float*)d_in[14];
    float* out = (float*)d_out;

    // ws layout (~8.95 MB): A1 aliases dead CTG+P2G region after kZ.
    char* ws = (char*)d_ws;
    float4* CTG = (float4*)ws;
    float2* P2G = (float2*)(ws + (size_t)BB*CC*16);
    __hip_bfloat16* A1 = (__hip_bfloat16*)ws;
    const size_t A1_BYTES = (size_t)BB*SROWS*CC*2;            // 7,864,320
    __hip_bfloat16* Zsb = (__hip_bfloat16*)(ws + A1_BYTES);
    float* Q = (float*)(ws + A1_BYTES + (size_t)(2*BB+1)*DD*2);

    hipMemsetAsync(Q, 0, (size_t)BB*SS*sizeof(float), stream);

    kS<<<dim3(BB), dim3(512), 0, stream>>>(
        sensor, Wsen, bsen, h1, h2, s1, s2, CTG, P2G);

    kZ<<<dim3(BB*NSL), dim3(ZT), 0, stream>>>(CTG, P2G, Zsb);

    // kA overwrites CTG/P2G (same stream => ordered after kZ)
    kA<<<dim3(BB, SROWS/16), dim3(384), 0, stream>>>(E, tok, s1, A1);

    kD<<<dim3(NWG), dim3(NTD), 0, stream>>>(
        A1, E, tok, h1, h2, s2, Ws2, bs2, Zsb, Q);

    kE<<<dim3(BB), dim3(256), 0, stream>>>(Q, Wout, bout, out);
}

// Round 12
// 261.245 us; speedup vs baseline: 1.0111x; 1.0111x over previous
//
#include <hip/hip_runtime.h>
#include <hip/hip_bf16.h>
#include <math.h>

#define DD 8192     // sketch dimension d
#define CC 768      // channels
#define SS 145      // sequence length
#define BB 32       // batch
#define SN 64       // sensor dim
#define SROWS 160   // padded s rows (10 tiles of 16)

// ---- kD geometry ----
#define TN 64            // e-cols per block
#define NET (CC/TN)      // 12 e-tiles
#define NSTEP (CC/32)    // 24 K-steps of 32
#define NTD 512          // 8 waves
#define NWG (NET*BB*3)   // 1152 blocks

// ---- kZ geometry ----
#define ZT 512           // threads
#define NSL 16           // d-slices per b -> 512 blocks

typedef __attribute__((ext_vector_type(8))) short short8;   // 8 bf16 (4 VGPR)
typedef __attribute__((ext_vector_type(4))) float f32x4;    // MFMA acc

// ---------------------------------------------------------------------------
// kS: per-b sketch build. u[b,c]=b_sen[c]+sensor·Wsen[c,:];
// CTG[b][c]=(u1, s1, bits(h1c), 0); P2G[b][t]=(S2u_b[t], S2s[t]).
// ---------------------------------------------------------------------------
__global__ __launch_bounds__(512) void kS(
    const float* __restrict__ sensor, const float* __restrict__ Wsen,
    const float* __restrict__ bsen,
    const int* __restrict__ h1, const int* __restrict__ h2,
    const int* __restrict__ s1, const int* __restrict__ s2,
    float4* __restrict__ CTG, float2* __restrict__ P2G)
{
    __shared__ float2 P2l[DD];        // 64 KB
    __shared__ float  sens[SN];
    const int b   = blockIdx.x;
    const int tid = threadIdx.x;

    if (tid < SN) sens[tid] = sensor[b*SN + tid];
    {
        float4* p4 = (float4*)P2l;
        #pragma unroll
        for (int i = 0; i < 8; ++i) p4[tid + i*512] = make_float4(0.f,0.f,0.f,0.f);
    }
    __syncthreads();

    for (int c = tid; c < CC; c += 512) {
        float u = bsen[c];
        const float4* w = (const float4*)(Wsen + (size_t)c*SN);
        #pragma unroll
        for (int n4 = 0; n4 < 16; ++n4) {
            float4 wv = w[n4];
            u += sens[4*n4+0]*wv.x + sens[4*n4+1]*wv.y
               + sens[4*n4+2]*wv.z + sens[4*n4+3]*wv.w;
        }
        float f1 = (float)s1[c], f2 = (float)s2[c];
        float4 ct;
        ct.x = u * f1; ct.y = f1; ct.z = __int_as_float(h1[c]); ct.w = 0.f;
        CTG[(size_t)b*CC + c] = ct;
        int t = h2[c];
        unsafeAtomicAdd(&P2l[t].x, u * f2);
        unsafeAtomicAdd(&P2l[t].y, f2);
    }
    __syncthreads();

    {
        const float4* p4 = (const float4*)P2l;
        float4* dst = (float4*)(P2G + (size_t)b*DD);
        #pragma unroll
        for (int i = 0; i < 8; ++i) dst[tid + i*512] = p4[tid + i*512];
    }
}

// ---------------------------------------------------------------------------
// kZ: gather-free Z build via shifted-sketch sums (unchanged).
//   Zuu_b[d]=sum_c u1[c]*S2u[(d-h1c)], Zcr_b[d]=sum u1*S2s+s1*S2u,
//   Z11[d]=sum s1*S2s (b==0 writes). Writes bf16 Zsb directly.
// ---------------------------------------------------------------------------
__global__ __launch_bounds__(ZT) void kZ(
    const float4* __restrict__ CTG, const float2* __restrict__ P2G,
    __hip_bfloat16* __restrict__ Zsb)
{
    __shared__ float2 P2l[DD];        // 64 KB -> 2 blocks/CU

    const int bid = blockIdx.x;
    const int wg  = (bid & 7)*(BB*NSL/8) + (bid >> 3);
    const int b   = wg >> 4;
    const int dsl = wg & (NSL-1);
    const int tid = threadIdx.x;

    {
        const float4* src = (const float4*)(P2G + (size_t)b*DD);
        float4* dst = (float4*)P2l;
        #pragma unroll
        for (int i = 0; i < 8; ++i) dst[tid + i*ZT] = src[tid + i*ZT];
    }
    __syncthreads();

    const int d = dsl*ZT + tid;
    const float4* ctp = CTG + (size_t)b*CC;
    float accU = 0.f, accC = 0.f, acc1 = 0.f;
    #pragma unroll 4
    for (int c = 0; c < CC; ++c) {
        float4 ct = ctp[c];                       // uniform -> s_load path
        int idx = (d - __float_as_int(ct.z)) & (DD-1);
        float2 p = P2l[idx];                      // conflict-free b64 gather
        accU = fmaf(ct.x, p.x, accU);
        accC = fmaf(ct.x, p.y, fmaf(ct.y, p.x, accC));
        acc1 = fmaf(ct.y, p.y, acc1);
    }

    Zsb[(size_t)b*DD + d]        = __float2bfloat16(accU);
    Zsb[(size_t)(BB + b)*DD + d] = __float2bfloat16(accC);
    if (b == 0) Zsb[(size_t)2*BB*DD + d] = __float2bfloat16(acc1);
}

// ---------------------------------------------------------------------------
// kA: precompute A1[b][sp][c] = bf16((E[b,sp,c]+tok1[c])*s1[c]), zero rows
// for sp>=SS. 7.9 MB, L2-resident for kD.
// ---------------------------------------------------------------------------
__global__ __launch_bounds__(384) void kA(
    const float* __restrict__ E, const float* __restrict__ tok,
    const int* __restrict__ s1, __hip_bfloat16* __restrict__ A1)
{
    const int b  = blockIdx.x;
    const int r0 = blockIdx.y * 16;
    const int p  = threadIdx.x;           // c-pair 0..383
    const int c  = 2*p;
    const float s1a = (float)s1[c], s1b = (float)s1[c+1];
    const float ta = tok[CC + c] * s1a, tb = tok[CC + c + 1] * s1b;
    #pragma unroll
    for (int rr = 0; rr < 16; ++rr) {
        int sp = r0 + rr;
        unsigned int word = 0;
        if (sp < SS) {
            float2 ev = *(const float2*)&E[((size_t)b*SS + sp)*CC + c];
            __hip_bfloat16 x0 = __float2bfloat16(ev.x*s1a + ta);
            __hip_bfloat16 x1 = __float2bfloat16(ev.y*s1b + tb);
            word = (unsigned int)*(unsigned short*)&x0
                 | ((unsigned int)*(unsigned short*)&x1 << 16);
        }
        *(unsigned int*)&A1[((size_t)b*SROWS + sp)*CC + c] = word;
    }
}

// ---------------------------------------------------------------------------
// kD: BARRIER-FREE bf16 MFMA quadratic forms.
// R11 showed kD is choreography-bound (2x occupancy -> 0 gain, VALU 12%):
// 24 barriers/block serialized every chunk on the slowest wave. This version
// has ONE barrier total (after the 16KB Zm + 1.5KB h1 LDS stage):
//  - B-fragments: in-register gather from Zm (lane-constant h2[eg]; h1 via
//    one broadcast ds_read_b128/step from the LDS h1 table).
//  - A-fragments: direct from bf16 A1 (L2-hot) into a named register double
//    buffer (bufA/bufB, 2-step-unrolled loop -> compile-time indices), loaded
//    one 32-K-step ahead so L2 latency hides under gather+MFMA of the
//    current step. No Lt, no WRITE, no vmcnt chokepoints.
// Waves fully independent after the stage barrier -> TLP/ILP finally apply.
//   m=0: w2^2*Zuu[b]  m=1: w2*bb*Zcr[b]  m=2: bb^2*Z11.
// LDS 17.9 KB; launch_bounds(512,2): no forced spill (~110 VGPR est).
// ---------------------------------------------------------------------------
__global__ __launch_bounds__(NTD, 2) void kD(
    const __hip_bfloat16* __restrict__ A1,
    const float* __restrict__ E, const float* __restrict__ tok,
    const int* __restrict__ h1, const int* __restrict__ h2,
    const int* __restrict__ s2,
    const float* __restrict__ Ws2, const float* __restrict__ bs2,
    const __hip_bfloat16* __restrict__ Zsb, float* __restrict__ Q)
{
    __shared__ __align__(16) unsigned short Zm[DD];    // 16384 B
    __shared__ __align__(16) unsigned short h1l[CC];   //  1536 B

    const int bid = blockIdx.x;
    const int wg  = (bid & 7)*(NWG/8) + (bid >> 3);
    const int b   = wg / (3*NET);
    const int r   = wg % (3*NET);
    const int m   = r / NET;
    const int et  = r % NET;
    const int tid = threadIdx.x;
    const int e0  = et * TN;

    // stage Zm (bf16, coalesced uint4) + h1 table; the ONLY barrier follows
    {
        const uint4* src = (const uint4*)(Zsb +
            (size_t)((m == 0) ? b : (m == 1) ? (BB + b) : 2*BB) * DD);
        uint4* dst = (uint4*)Zm;
        dst[tid]       = src[tid];
        dst[tid + NTD] = src[tid + NTD];
    }
    for (int c = tid; c < CC; c += NTD) h1l[c] = (unsigned short)h1[c];
    __syncthreads();

    const int lane = tid & 63;
    const int w    = tid >> 6;        // wave 0..7
    const int eT   = w & 3;           // e-tile within block
    const int sB   = (w >> 2) * 5;    // first s-tile
    const int l15  = lane & 15;
    const int l4   = lane >> 4;

    const int eg   = e0 + eT*16 + l15;   // this lane's e column
    const int myh2 = h2[eg];             // lane-constant gather offset

    // per-lane A base: row = b*160 + sB*16 + l15, k-offset l4*8
    const __hip_bfloat16* Abase =
        A1 + ((size_t)(b*SROWS + sB*16 + l15))*CC + l4*8;

#define LOADA(BUF, ST) { \
    _Pragma("unroll") \
    for (int t = 0; t < 5; ++t) \
        BUF[t] = *(const short8*)(Abase + (size_t)t*16*CC + (ST)*32); \
    }

#define GM(BUF, ST) { \
    const uint4 hv = *(const uint4*)&h1l[(ST)*32 + l4*8]; \
    unsigned int g0 = Zm[((hv.x & 0xffff) + myh2) & (DD-1)]; \
    unsigned int g1 = Zm[((hv.x >> 16)    + myh2) & (DD-1)]; \
    unsigned int g2 = Zm[((hv.y & 0xffff) + myh2) & (DD-1)]; \
    unsigned int g3 = Zm[((hv.y >> 16)    + myh2) & (DD-1)]; \
    unsigned int g4 = Zm[((hv.z & 0xffff) + myh2) & (DD-1)]; \
    unsigned int g5 = Zm[((hv.z >> 16)    + myh2) & (DD-1)]; \
    unsigned int g6 = Zm[((hv.w & 0xffff) + myh2) & (DD-1)]; \
    unsigned int g7 = Zm[((hv.w >> 16)    + myh2) & (DD-1)]; \
    union { unsigned int u[4]; short8 s; } bf; \
    bf.u[0] = g0 | (g1 << 16); \
    bf.u[1] = g2 | (g3 << 16); \
    bf.u[2] = g4 | (g5 << 16); \
    bf.u[3] = g6 | (g7 << 16); \
    _Pragma("unroll") \
    for (int t = 0; t < 5; ++t) \
        acc[t] = __builtin_amdgcn_mfma_f32_16x16x32_bf16( \
            BUF[t], bf.s, acc[t], 0, 0, 0); \
    }

    f32x4 acc[5];
    #pragma unroll
    for (int t = 0; t < 5; ++t) acc[t] = (f32x4){0.f, 0.f, 0.f, 0.f};

    short8 bufA[5], bufB[5];
    LOADA(bufA, 0)
    #pragma unroll 1
    for (int st = 0; st < NSTEP; st += 2) {
        if (st + 1 < NSTEP) LOADA(bufB, st + 1)
        GM(bufA, st)
        if (st + 2 < NSTEP) LOADA(bufA, st + 2)
        if (st + 1 < NSTEP) GM(bufB, st + 1)
    }
#undef LOADA
#undef GM

    // --- epilogue: q[s] = sum_e acc * a2[s,e]; reduce 16 e-lanes; scale; add ---
    const float s2e = (float)s2[eg];
    const float t2e = tok[CC + eg] * s2e;
    #pragma unroll
    for (int t = 0; t < 5; ++t) {
        #pragma unroll
        for (int rr = 0; rr < 4; ++rr) {
            int s = (sB + t)*16 + l4*4 + rr;
            float qv = 0.f;
            if (s < SS) {
                float a2v = E[((size_t)b*SS + s)*CC + eg] * s2e + t2e;
                qv = acc[t][rr] * a2v;
            }
            qv += __shfl_xor(qv, 1);
            qv += __shfl_xor(qv, 2);
            qv += __shfl_xor(qv, 4);
            qv += __shfl_xor(qv, 8);
            if (l15 == 0 && s < SS) {
                float w2v = Ws2[s], bbv = bs2[s];
                float sc  = (m == 0) ? w2v*w2v : (m == 1) ? w2v*bbv : bbv*bbv;
                unsafeAtomicAdd(&Q[b*SS + s], sc * qv);
            }
        }
    }
}

// ---------------------------------------------------------------------------
// kE: bp = sign(Q)*sqrt(|Q|+1e-5); L2-normalize over s; project W_out.
// ---------------------------------------------------------------------------
__global__ __launch_bounds__(256) void kE(
    const float* __restrict__ Q, const float* __restrict__ Wout,
    const float* __restrict__ bout, float* __restrict__ out)
{
    __shared__ float red[8];
    const int b = blockIdx.x, tid = threadIdx.x;
    float v = 0.f, w = 0.f;
    if (tid < SS) {
        float ip = Q[b*SS + tid];
        float sg = (ip > 0.f) ? 1.f : ((ip < 0.f) ? -1.f : 0.f);
        v = sg * sqrtf(fabsf(ip) + 1e-5f);
        w = v * Wout[tid];
    }
    float sq = v * v;
    #pragma unroll
    for (int off = 32; off > 0; off >>= 1) {
        sq += __shfl_down(sq, off, 64);
        w  += __shfl_down(w,  off, 64);
    }
    if ((tid & 63) == 0) { red[tid >> 6] = sq; red[4 + (tid >> 6)] = w; }
    __syncthreads();
    if (tid == 0) {
        float ssq  = red[0] + red[1] + red[2] + red[3];
        float sw   = red[4] + red[5] + red[6] + red[7];
        float norm = fmaxf(sqrtf(ssq), 1e-12f);
        out[b] = sw / norm + bout[0];
    }
}

// ---------------------------------------------------------------------------
extern "C" void kernel_launch(void* const* d_in, const int* in_sizes, int n_in,
                              void* d_out, int out_size, void* d_ws, size_t ws_size,
                              hipStream_t stream) {
    const float* sensor = (const float*)d_in[0];
    const float* E      = (const float*)d_in[1];
    const int*   h1     = (const int*)d_in[3];
    const int*   h2     = (const int*)d_in[4];
    const int*   s1     = (const int*)d_in[5];
    const int*   s2     = (const int*)d_in[6];
    const float* Wsen   = (const float*)d_in[8];
    const float* bsen   = (const float*)d_in[9];
    const float* Ws2    = (const float*)d_in[10];
    const float* bs2    = (const float*)d_in[11];
    const float* Wout   = (const float*)d_in[12];
    const float* bout   = (const float*)d_in[13];
    const float* tok    = (const float*)d_in[14];
    float* out = (float*)d_out;

    // ws layout (~8.95 MB): A1 aliases dead CTG+P2G region after kZ.
    char* ws = (char*)d_ws;
    float4* CTG = (float4*)ws;
    float2* P2G = (float2*)(ws + (size_t)BB*CC*16);
    __hip_bfloat16* A1 = (__hip_bfloat16*)ws;
    const size_t A1_BYTES = (size_t)BB*SROWS*CC*2;            // 7,864,320
    __hip_bfloat16* Zsb = (__hip_bfloat16*)(ws + A1_BYTES);
    float* Q = (float*)(ws + A1_BYTES + (size_t)(2*BB+1)*DD*2);

    hipMemsetAsync(Q, 0, (size_t)BB*SS*sizeof(float), stream);

    kS<<<dim3(BB), dim3(512), 0, stream>>>(
        sensor, Wsen, bsen, h1, h2, s1, s2, CTG, P2G);

    kZ<<<dim3(BB*NSL), dim3(ZT), 0, stream>>>(CTG, P2G, Zsb);

    // kA overwrites CTG/P2G (same stream => ordered after kZ)
    kA<<<dim3(BB, SROWS/16), dim3(384), 0, stream>>>(E, tok, s1, A1);

    kD<<<dim3(NWG), dim3(NTD), 0, stream>>>(
        A1, E, tok, h1, h2, s2, Ws2, bs2, Zsb, Q);

    kE<<<dim3(BB), dim3(256), 0, stream>>>(Q, Wout, bout, out);
}

// Round 13
// 244.616 us; speedup vs baseline: 1.0798x; 1.0680x over previous
//
#include <hip/hip_runtime.h>
#include <hip/hip_bf16.h>
#include <math.h>

#define DD 8192     // sketch dimension d
#define CC 768      // channels
#define SS 145      // sequence length
#define BB 32       // batch
#define SN 64       // sensor dim
#define SROWS 160   // padded s rows (10 tiles of 16)

// ---- kD geometry ----
#define TN 128           // e-cols per block (8 waves x 16)
#define NET (CC/TN)      // 6 e-tiles
#define CKD 32           // c per chunk
#define NCHK (CC/CKD)    // 24 chunks
#define MTW 40           // Mt row stride in ushort (80 B: 64 data + 16 pad)
#define NTD 512          // 8 waves
#define NWG (NET*BB*3)   // 576 blocks

// ---- kZ geometry ----
#define ZT 512           // threads
#define NSL 16           // d-slices per b -> 512 blocks

typedef __attribute__((ext_vector_type(8))) short short8;   // 8 bf16 (4 VGPR)
typedef __attribute__((ext_vector_type(4))) float f32x4;    // MFMA acc

// async 16B global -> LDS DMA (dest = wave-uniform base + lane*16)
__device__ __forceinline__ void gload16(const void* g, void* l) {
    __builtin_amdgcn_global_load_lds(
        (const __attribute__((address_space(1))) unsigned int*)g,
        (__attribute__((address_space(3))) unsigned int*)l, 16, 0, 0);
}

// ---------------------------------------------------------------------------
// kS: per-b sketch build. u[b,c]=b_sen[c]+sensor·Wsen[c,:];
// CTG[b][c]=(u1, s1, bits(h1c), 0); P2G[b][t]=(S2u_b[t], S2s[t]).
// ---------------------------------------------------------------------------
__global__ __launch_bounds__(512) void kS(
    const float* __restrict__ sensor, const float* __restrict__ Wsen,
    const float* __restrict__ bsen,
    const int* __restrict__ h1, const int* __restrict__ h2,
    const int* __restrict__ s1, const int* __restrict__ s2,
    float4* __restrict__ CTG, float2* __restrict__ P2G)
{
    __shared__ float2 P2l[DD];        // 64 KB
    __shared__ float  sens[SN];
    const int b   = blockIdx.x;
    const int tid = threadIdx.x;

    if (tid < SN) sens[tid] = sensor[b*SN + tid];
    {
        float4* p4 = (float4*)P2l;
        #pragma unroll
        for (int i = 0; i < 8; ++i) p4[tid + i*512] = make_float4(0.f,0.f,0.f,0.f);
    }
    __syncthreads();

    for (int c = tid; c < CC; c += 512) {
        float u = bsen[c];
        const float4* w = (const float4*)(Wsen + (size_t)c*SN);
        #pragma unroll
        for (int n4 = 0; n4 < 16; ++n4) {
            float4 wv = w[n4];
            u += sens[4*n4+0]*wv.x + sens[4*n4+1]*wv.y
               + sens[4*n4+2]*wv.z + sens[4*n4+3]*wv.w;
        }
        float f1 = (float)s1[c], f2 = (float)s2[c];
        float4 ct;
        ct.x = u * f1; ct.y = f1; ct.z = __int_as_float(h1[c]); ct.w = 0.f;
        CTG[(size_t)b*CC + c] = ct;
        int t = h2[c];
        unsafeAtomicAdd(&P2l[t].x, u * f2);
        unsafeAtomicAdd(&P2l[t].y, f2);
    }
    __syncthreads();

    {
        const float4* p4 = (const float4*)P2l;
        float4* dst = (float4*)(P2G + (size_t)b*DD);
        #pragma unroll
        for (int i = 0; i < 8; ++i) dst[tid + i*512] = p4[tid + i*512];
    }
}

// ---------------------------------------------------------------------------
// kZ: gather-free Z build via shifted-sketch sums (unchanged).
// ---------------------------------------------------------------------------
__global__ __launch_bounds__(ZT) void kZ(
    const float4* __restrict__ CTG, const float2* __restrict__ P2G,
    __hip_bfloat16* __restrict__ Zsb)
{
    __shared__ float2 P2l[DD];        // 64 KB -> 2 blocks/CU

    const int bid = blockIdx.x;
    const int wg  = (bid & 7)*(BB*NSL/8) + (bid >> 3);
    const int b   = wg >> 4;
    const int dsl = wg & (NSL-1);
    const int tid = threadIdx.x;

    {
        const float4* src = (const float4*)(P2G + (size_t)b*DD);
        float4* dst = (float4*)P2l;
        #pragma unroll
        for (int i = 0; i < 8; ++i) dst[tid + i*ZT] = src[tid + i*ZT];
    }
    __syncthreads();

    const int d = dsl*ZT + tid;
    const float4* ctp = CTG + (size_t)b*CC;
    float accU = 0.f, accC = 0.f, acc1 = 0.f;
    #pragma unroll 4
    for (int c = 0; c < CC; ++c) {
        float4 ct = ctp[c];                       // uniform -> s_load path
        int idx = (d - __float_as_int(ct.z)) & (DD-1);
        float2 p = P2l[idx];                      // conflict-free b64 gather
        accU = fmaf(ct.x, p.x, accU);
        accC = fmaf(ct.x, p.y, fmaf(ct.y, p.x, accC));
        acc1 = fmaf(ct.y, p.y, acc1);
    }

    Zsb[(size_t)b*DD + d]        = __float2bfloat16(accU);
    Zsb[(size_t)(BB + b)*DD + d] = __float2bfloat16(accC);
    if (b == 0) Zsb[(size_t)2*BB*DD + d] = __float2bfloat16(acc1);
}

// ---------------------------------------------------------------------------
// kA: precompute A-panel in CHUNK-MAJOR SWIZZLED layout for kD's
// global_load_lds staging:
//   A1[b][ck][row][64B], word for (row, c2) stored at granule
//   g' = (c2>>2) ^ (row&3)  (bijective within the 4 granules of a 64B row).
// Linear DMA into LDS then yields conflict-free ds_read_b128 afrags.
// value = bf16((E[b,row,c]+tok1[c])*s1[c]); rows >= SS are zero.
// ---------------------------------------------------------------------------
__global__ __launch_bounds__(384) void kA(
    const float* __restrict__ E, const float* __restrict__ tok,
    const int* __restrict__ s1, unsigned int* __restrict__ A1u)
{
    const int b  = blockIdx.x;
    const int r0 = blockIdx.y * 16;
    const int p  = threadIdx.x;           // c-pair 0..383
    const int c  = 2*p;
    const int ck = p >> 4;                // chunk 0..23
    const int c2 = p & 15;                // word within chunk-row
    const float s1a = (float)s1[c], s1b = (float)s1[c+1];
    const float ta = tok[CC + c] * s1a, tb = tok[CC + c + 1] * s1b;
    #pragma unroll
    for (int rr = 0; rr < 16; ++rr) {
        int row = r0 + rr;
        unsigned int word = 0;
        if (row < SS) {
            float2 ev = *(const float2*)&E[((size_t)b*SS + row)*CC + c];
            __hip_bfloat16 x0 = __float2bfloat16(ev.x*s1a + ta);
            __hip_bfloat16 x1 = __float2bfloat16(ev.y*s1b + tb);
            word = (unsigned int)*(unsigned short*)&x0
                 | ((unsigned int)*(unsigned short*)&x1 << 16);
        }
        int gp = (c2 >> 2) ^ (row & 3);   // swizzled granule
        A1u[((size_t)(b*NCHK + ck)*SROWS + row)*16 + gp*4 + (c2 & 3)] = word;
    }
}

// ---------------------------------------------------------------------------
// kD: m97-pattern MFMA GEMM with gathered B.
// Block = (b,m,et): 160s x 128e x 768c. 8 waves: wave w owns e-sub-tile
// w (16 cols) x all 10 s-tiles -> 10 MFMA per B-fragment.
// Per chunk (CKD=32): issue global_load_lds DMA of A-chunk(next) (swizzled
// linear copy, no VGPR roundtrip) + LDS-gather Mt(next) from Zm, THEN MFMA
// on current buffers, one barrier. Loads fly during MFMA (m97 schedule).
//   m=0: w2^2*Zuu[b]  m=1: w2*bb*Zcr[b]  m=2: bb^2*Z11.
// LDS 57.5 KB -> 2 blocks/CU; launch_bounds(512,4): VGPR cap 128 (~90 est).
// ---------------------------------------------------------------------------
__global__ __launch_bounds__(NTD, 4) void kD(
    const unsigned int* __restrict__ A1u,
    const float* __restrict__ E, const float* __restrict__ tok,
    const int* __restrict__ h1, const int* __restrict__ h2,
    const int* __restrict__ s2,
    const float* __restrict__ Ws2, const float* __restrict__ bs2,
    const __hip_bfloat16* __restrict__ Zsb, float* __restrict__ Q)
{
    __shared__ __align__(16) unsigned short Zm[DD];          // 16384 B
    __shared__ __align__(16) unsigned short Lt[2][SROWS*32]; // 2x10240 B
    __shared__ __align__(16) unsigned short Mt[2][TN*MTW];   // 2x10240 B
    __shared__ unsigned short h1l[CC];                       //  1536 B
    // total 58880 B -> 2 blocks/CU

    const int bid = blockIdx.x;
    const int wg  = (bid & 7)*(NWG/8) + (bid >> 3);
    const int b   = wg / (3*NET);
    const int r   = wg % (3*NET);
    const int m   = r / NET;
    const int et  = r % NET;
    const int tid = threadIdx.x;
    const int e0  = et * TN;

    // ---- stage Zm + h1 table ----
    {
        const uint4* src = (const uint4*)(Zsb +
            (size_t)((m == 0) ? b : (m == 1) ? (BB + b) : 2*BB) * DD);
        uint4* dst = (uint4*)Zm;
        dst[tid]       = src[tid];
        dst[tid + NTD] = src[tid + NTD];
    }
    for (int c = tid; c < CC; c += NTD) h1l[c] = (unsigned short)h1[c];

    const int lane = tid & 63;
    const int wv   = tid >> 6;        // wave 0..7 (= e-sub-tile)
    const int l15  = lane & 15;
    const int l4   = lane >> 4;

    // gather thread-constants: 4 words/thread/chunk at (c2, e)
    int gc2[4], ge[4], gh2[4];
    #pragma unroll
    for (int j = 0; j < 4; ++j) {
        int idx = tid + j*512;
        gc2[j] = idx >> 7;            // 0..15
        ge[j]  = idx & 127;           // 0..127
        gh2[j] = h2[e0 + ge[j]];
    }
    __syncthreads();

    const char* Abase = (const char*)A1u + (size_t)b*NCHK*SROWS*64;

#define STAGE_A(CKK, BUF) { \
    const char* cbase = Abase + (size_t)(CKK)*SROWS*64; \
    gload16(cbase + wv*1024 + lane*16, (char*)(BUF) + wv*1024); \
    if (wv < 2) \
        gload16(cbase + 8192 + wv*1024 + lane*16, \
                (char*)(BUF) + 8192 + wv*1024); \
    }

#define GATHER(CKK, BUF) { \
    const int cb = (CKK)*CKD; \
    _Pragma("unroll") \
    for (int j = 0; j < 4; ++j) { \
        unsigned hw = *(const unsigned*)&h1l[cb + 2*gc2[j]]; \
        unsigned lo = Zm[((int)(hw & 0xffff) + gh2[j]) & (DD-1)]; \
        unsigned hi = Zm[((int)(hw >> 16)    + gh2[j]) & (DD-1)]; \
        *(unsigned*)&BUF[ge[j]*MTW + 2*gc2[j]] = lo | (hi << 16); \
    } }

    f32x4 acc[10];
    #pragma unroll
    for (int t = 0; t < 10; ++t) acc[t] = (f32x4){0.f, 0.f, 0.f, 0.f};

    STAGE_A(0, Lt[0])
    GATHER(0, Mt[0])
    __syncthreads();                  // drains DMA + gather for chunk 0

    for (int ck = 0; ck < NCHK; ++ck) {
        const int cur = ck & 1;
        if (ck + 1 < NCHK) {
            STAGE_A(ck + 1, Lt[cur ^ 1])   // async DMA, flies during MFMA
            GATHER(ck + 1, Mt[cur ^ 1])
        }

        __builtin_amdgcn_s_setprio(1);
        short8 bfrag = *(const short8*)&Mt[cur][(wv*16 + l15)*MTW + l4*8];
        #pragma unroll
        for (int t = 0; t < 10; ++t) {
            int R = t*16 + l15;
            short8 afrag = *(const short8*)&Lt[cur][R*32 + ((l4 ^ (R & 3))*8)];
            acc[t] = __builtin_amdgcn_mfma_f32_16x16x32_bf16(
                afrag, bfrag, acc[t], 0, 0, 0);
        }
        __builtin_amdgcn_s_setprio(0);
        __syncthreads();              // next-chunk buffers ready after this
    }
#undef STAGE_A
#undef GATHER

    // --- epilogue: q[s] = sum_e acc * a2[s,e]; reduce 16 e-lanes; scale; add ---
    const int   eg  = e0 + wv*16 + l15;
    const float s2e = (float)s2[eg];
    const float t2e = tok[CC + eg] * s2e;
    #pragma unroll
    for (int t = 0; t < 10; ++t) {
        #pragma unroll
        for (int rr = 0; rr < 4; ++rr) {
            int s = t*16 + l4*4 + rr;
            float qv = 0.f;
            if (s < SS) {
                float a2v = E[((size_t)b*SS + s)*CC + eg] * s2e + t2e;
                qv = acc[t][rr] * a2v;
            }
            qv += __shfl_xor(qv, 1);
            qv += __shfl_xor(qv, 2);
            qv += __shfl_xor(qv, 4);
            qv += __shfl_xor(qv, 8);
            if (l15 == 0 && s < SS) {
                float w2v = Ws2[s], bbv = bs2[s];
                float sc  = (m == 0) ? w2v*w2v : (m == 1) ? w2v*bbv : bbv*bbv;
                unsafeAtomicAdd(&Q[b*SS + s], sc * qv);
            }
        }
    }
}

// ---------------------------------------------------------------------------
// kE: bp = sign(Q)*sqrt(|Q|+1e-5); L2-normalize over s; project W_out.
// ---------------------------------------------------------------------------
__global__ __launch_bounds__(256) void kE(
    const float* __restrict__ Q, const float* __restrict__ Wout,
    const float* __restrict__ bout, float* __restrict__ out)
{
    __shared__ float red[8];
    const int b = blockIdx.x, tid = threadIdx.x;
    float v = 0.f, w = 0.f;
    if (tid < SS) {
        float ip = Q[b*SS + tid];
        float sg = (ip > 0.f) ? 1.f : ((ip < 0.f) ? -1.f : 0.f);
        v = sg * sqrtf(fabsf(ip) + 1e-5f);
        w = v * Wout[tid];
    }
    float sq = v * v;
    #pragma unroll
    for (int off = 32; off > 0; off >>= 1) {
        sq += __shfl_down(sq, off, 64);
        w  += __shfl_down(w,  off, 64);
    }
    if ((tid & 63) == 0) { red[tid >> 6] = sq; red[4 + (tid >> 6)] = w; }
    __syncthreads();
    if (tid == 0) {
        float ssq  = red[0] + red[1] + red[2] + red[3];
        float sw   = red[4] + red[5] + red[6] + red[7];
        float norm = fmaxf(sqrtf(ssq), 1e-12f);
        out[b] = sw / norm + bout[0];
    }
}

// ---------------------------------------------------------------------------
extern "C" void kernel_launch(void* const* d_in, const int* in_sizes, int n_in,
                              void* d_out, int out_size, void* d_ws, size_t ws_size,
                              hipStream_t stream) {
    const float* sensor = (const float*)d_in[0];
    const float* E      = (const float*)d_in[1];
    const int*   h1     = (const int*)d_in[3];
    const int*   h2     = (const int*)d_in[4];
    const int*   s1     = (const int*)d_in[5];
    const int*   s2     = (const int*)d_in[6];
    const float* Wsen   = (const float*)d_in[8];
    const float* bsen   = (const float*)d_in[9];
    const float* Ws2    = (const float*)d_in[10];
    const float* bs2    = (const float*)d_in[11];
    const float* Wout   = (const float*)d_in[12];
    const float* bout   = (const float*)d_in[13];
    const float* tok    = (const float*)d_in[14];
    float* out = (float*)d_out;

    // ws layout (~8.95 MB): A1 (chunk-major swizzled) aliases dead CTG+P2G
    // region after kZ.
    char* ws = (char*)d_ws;
    float4* CTG = (float4*)ws;
    float2* P2G = (float2*)(ws + (size_t)BB*CC*16);
    unsigned int* A1u = (unsigned int*)ws;
    const size_t A1_BYTES = (size_t)BB*NCHK*SROWS*64;         // 7,864,320
    __hip_bfloat16* Zsb = (__hip_bfloat16*)(ws + A1_BYTES);
    float* Q = (float*)(ws + A1_BYTES + (size_t)(2*BB+1)*DD*2);

    hipMemsetAsync(Q, 0, (size_t)BB*SS*sizeof(float), stream);

    kS<<<dim3(BB), dim3(512), 0, stream>>>(
        sensor, Wsen, bsen, h1, h2, s1, s2, CTG, P2G);

    kZ<<<dim3(BB*NSL), dim3(ZT), 0, stream>>>(CTG, P2G, Zsb);

    // kA overwrites CTG/P2G (same stream => ordered after kZ)
    kA<<<dim3(BB, SROWS/16), dim3(384), 0, stream>>>(E, tok, s1, A1u);

    kD<<<dim3(NWG), dim3(NTD), 0, stream>>>(
        A1u, E, tok, h1, h2, s2, Ws2, bs2, Zsb, Q);

    kE<<<dim3(BB), dim3(256), 0, stream>>>(Q, Wout, bout, out);
}

// Round 14
// 170.945 us; speedup vs baseline: 1.5451x; 1.4310x over previous
//
#include <hip/hip_runtime.h>
#include <hip/hip_bf16.h>
#include <math.h>

#define DD 8192     // sketch dimension d
#define CC 768      // channels
#define SS 145      // sequence length
#define BB 32       // batch
#define SN 64       // sensor dim
#define SROWS 160   // padded s rows (10 tiles of 16)
#define NCKA 24     // A1u chunks (kA layout, 32 c each)

// ---- kD geometry ----
#define NETD 12          // e-tiles of 64
#define NCH 12           // chunks per block (one c-half)
#define M01W 36          // Mt01 row stride in u32 (144 B)
#define NWGD (BB*2*NETD) // 768 blocks

// ---- kZ geometry ----
#define ZT 512
#define NSL 16

typedef __attribute__((ext_vector_type(8))) short short8;   // 8 bf16
typedef __attribute__((ext_vector_type(4))) float f32x4;    // MFMA acc

__device__ __forceinline__ void gload16(const void* g, void* l) {
    __builtin_amdgcn_global_load_lds(
        (const __attribute__((address_space(1))) unsigned int*)g,
        (__attribute__((address_space(3))) unsigned int*)l, 16, 0, 0);
}

// ---------------------------------------------------------------------------
// kS: per-b sketch build (unchanged). u[b,c]=b_sen[c]+sensor·Wsen[c,:];
// CTG[b][c]=(u1, s1, bits(h1c), 0); P2G[b][t]=(S2u_b[t], S2s[t]).
// ---------------------------------------------------------------------------
__global__ __launch_bounds__(512) void kS(
    const float* __restrict__ sensor, const float* __restrict__ Wsen,
    const float* __restrict__ bsen,
    const int* __restrict__ h1, const int* __restrict__ h2,
    const int* __restrict__ s1, const int* __restrict__ s2,
    float4* __restrict__ CTG, float2* __restrict__ P2G)
{
    __shared__ float2 P2l[DD];
    __shared__ float  sens[SN];
    const int b   = blockIdx.x;
    const int tid = threadIdx.x;

    if (tid < SN) sens[tid] = sensor[b*SN + tid];
    {
        float4* p4 = (float4*)P2l;
        #pragma unroll
        for (int i = 0; i < 8; ++i) p4[tid + i*512] = make_float4(0.f,0.f,0.f,0.f);
    }
    __syncthreads();

    for (int c = tid; c < CC; c += 512) {
        float u = bsen[c];
        const float4* w = (const float4*)(Wsen + (size_t)c*SN);
        #pragma unroll
        for (int n4 = 0; n4 < 16; ++n4) {
            float4 wv = w[n4];
            u += sens[4*n4+0]*wv.x + sens[4*n4+1]*wv.y
               + sens[4*n4+2]*wv.z + sens[4*n4+3]*wv.w;
        }
        float f1 = (float)s1[c], f2 = (float)s2[c];
        float4 ct;
        ct.x = u * f1; ct.y = f1; ct.z = __int_as_float(h1[c]); ct.w = 0.f;
        CTG[(size_t)b*CC + c] = ct;
        int t = h2[c];
        unsafeAtomicAdd(&P2l[t].x, u * f2);
        unsafeAtomicAdd(&P2l[t].y, f2);
    }
    __syncthreads();

    {
        const float4* p4 = (const float4*)P2l;
        float4* dst = (float4*)(P2G + (size_t)b*DD);
        #pragma unroll
        for (int i = 0; i < 8; ++i) dst[tid + i*512] = p4[tid + i*512];
    }
}

// ---------------------------------------------------------------------------
// kZ: shifted-sketch Z build. NOW writes ZP[b][d] = pack(bf16 Zuu, bf16 Zcr)
// (u32) and, from b==0 blocks, Z11b[d] = bf16 Z11.
// ---------------------------------------------------------------------------
__global__ __launch_bounds__(ZT) void kZ(
    const float4* __restrict__ CTG, const float2* __restrict__ P2G,
    unsigned int* __restrict__ ZP, unsigned short* __restrict__ Z11b)
{
    __shared__ float2 P2l[DD];        // 64 KB

    const int bid = blockIdx.x;
    const int wg  = (bid & 7)*(BB*NSL/8) + (bid >> 3);
    const int b   = wg >> 4;
    const int dsl = wg & (NSL-1);
    const int tid = threadIdx.x;

    {
        const float4* src = (const float4*)(P2G + (size_t)b*DD);
        float4* dst = (float4*)P2l;
        #pragma unroll
        for (int i = 0; i < 8; ++i) dst[tid + i*ZT] = src[tid + i*ZT];
    }
    __syncthreads();

    const int d = dsl*ZT + tid;
    const float4* ctp = CTG + (size_t)b*CC;
    float accU = 0.f, accC = 0.f, acc1 = 0.f;
    #pragma unroll 4
    for (int c = 0; c < CC; ++c) {
        float4 ct = ctp[c];
        int idx = (d - __float_as_int(ct.z)) & (DD-1);
        float2 p = P2l[idx];
        accU = fmaf(ct.x, p.x, accU);
        accC = fmaf(ct.x, p.y, fmaf(ct.y, p.x, accC));
        acc1 = fmaf(ct.y, p.y, acc1);
    }

    __hip_bfloat16 zu = __float2bfloat16(accU);
    __hip_bfloat16 zc = __float2bfloat16(accC);
    ZP[(size_t)b*DD + d] = (unsigned int)*(unsigned short*)&zu
                         | ((unsigned int)*(unsigned short*)&zc << 16);
    if (b == 0) {
        __hip_bfloat16 z1 = __float2bfloat16(acc1);
        Z11b[d] = *(unsigned short*)&z1;
    }
}

// ---------------------------------------------------------------------------
// kA: A-panel, chunk-major swizzled (unchanged from R13):
//   A1u[b][ck][row][16 u32], word (row,c2) at granule g'=(c2>>2)^(row&3).
// ---------------------------------------------------------------------------
__global__ __launch_bounds__(384) void kA(
    const float* __restrict__ E, const float* __restrict__ tok,
    const int* __restrict__ s1, unsigned int* __restrict__ A1u)
{
    const int b  = blockIdx.x;
    const int r0 = blockIdx.y * 16;
    const int p  = threadIdx.x;
    const int c  = 2*p;
    const int ck = p >> 4;
    const int c2 = p & 15;
    const float s1a = (float)s1[c], s1b = (float)s1[c+1];
    const float ta = tok[CC + c] * s1a, tb = tok[CC + c + 1] * s1b;
    #pragma unroll
    for (int rr = 0; rr < 16; ++rr) {
        int row = r0 + rr;
        unsigned int word = 0;
        if (row < SS) {
            float2 ev = *(const float2*)&E[((size_t)b*SS + row)*CC + c];
            __hip_bfloat16 x0 = __float2bfloat16(ev.x*s1a + ta);
            __hip_bfloat16 x1 = __float2bfloat16(ev.y*s1b + tb);
            word = (unsigned int)*(unsigned short*)&x0
                 | ((unsigned int)*(unsigned short*)&x1 << 16);
        }
        int gp = (c2 >> 2) ^ (row & 3);
        A1u[((size_t)(b*NCKA + ck)*SROWS + row)*16 + gp*4 + (c2 & 3)] = word;
    }
}

// ---------------------------------------------------------------------------
// kM11: materialize the b-INDEPENDENT m=2 matrix once:
//   M11[ck][e][c2] = Z11[(h1[ck*32+c]+h2[e]) & 8191], bf16, row=32c=64 B.
// 24 blocks; Z11 staged in LDS; u32-pair writes.
// ---------------------------------------------------------------------------
__global__ __launch_bounds__(512) void kM11(
    const unsigned short* __restrict__ Z11b,
    const int* __restrict__ h1, const int* __restrict__ h2,
    unsigned int* __restrict__ M11u)
{
    __shared__ unsigned short Z11l[DD];   // 16 KB
    const int ck  = blockIdx.x;
    const int tid = threadIdx.x;
    {
        const uint4* src = (const uint4*)Z11b;
        uint4* dst = (uint4*)Z11l;
        #pragma unroll
        for (int i = 0; i < 2; ++i) dst[tid + i*512] = src[tid + i*512];
    }
    __syncthreads();

    const int hA = h1[ck*32 + 2*(tid & 15)];
    const int hB = h1[ck*32 + 2*(tid & 15) + 1];
    const int cp = tid & 15;
    #pragma unroll 4
    for (int i = 0; i < 24; ++i) {
        int idx = tid + i*512;              // 12288 u32 slots
        int ep  = idx >> 4;                 // 0..767
        int cpp = idx & 15;
        int ha = (cpp == cp) ? hA : h1[ck*32 + 2*cpp];
        int hb = (cpp == cp) ? hB : h1[ck*32 + 2*cpp + 1];
        int he = h2[ep];
        unsigned int lo = Z11l[(ha + he) & (DD-1)];
        unsigned int hi = Z11l[(hb + he) & (DD-1)];
        M11u[((size_t)ck*768 + ep)*16 + cpp] = lo | (hi << 16);
    }
}

// ---------------------------------------------------------------------------
// kD: fused 3-form MFMA. Block=(b, c-half, et64). 8 waves = 4 e-subs x 2
// s-halves; wave computes 16e x 80s x 3m (15 MFMA/chunk). Per chunk (32 c):
//  - A: global_load_lds DMA from swizzled A1u (next), LDS dbuf.
//  - m0,m1: ONE u32 gather/(c,e) from packed ZPl -> Mt01 dbuf; bfrags
//    unpacked in VALU (lo=Zuu, hi=Zcr).
//  - m2: bfrag direct from L2-hot M11 into named reg dbuf (bqA/bqB).
// One barrier per chunk. Epilogue: qv = (w2^2 a0 + w2 bb a1 + bb^2 a2)*a2v,
// one shfl-reduce + ONE atomic. LDS 73.2 KB -> 2 blocks/CU; (512,4) VGPR<=128.
// ---------------------------------------------------------------------------
__global__ __launch_bounds__(512, 4) void kD(
    const unsigned int* __restrict__ A1u,
    const unsigned short* __restrict__ M11,
    const float* __restrict__ E, const float* __restrict__ tok,
    const int* __restrict__ h1, const int* __restrict__ h2,
    const int* __restrict__ s2,
    const float* __restrict__ Ws2, const float* __restrict__ bs2,
    const unsigned int* __restrict__ ZP, float* __restrict__ Q)
{
    __shared__ __align__(16) unsigned int   ZPl[DD];           // 32768 B
    __shared__ __align__(16) unsigned short Lt[2][SROWS*32];   // 20480 B
    __shared__ __align__(16) unsigned int   Mt01[2][64*M01W];  // 18432 B
    __shared__ unsigned short h1l[CC];                         //  1536 B
    // total 73216 B -> 2 blocks/CU

    const int bid = blockIdx.x;
    const int wg  = (bid & 7)*(NWGD/8) + (bid >> 3);
    const int b   = wg / 24;
    const int r   = wg % 24;
    const int ch  = r / 12;
    const int et  = r % 12;
    const int tid = threadIdx.x;
    const int e0  = et * 64;
    const int cb0 = ch * 384;

    {
        const uint4* src = (const uint4*)(ZP + (size_t)b*DD);
        uint4* dst = (uint4*)ZPl;
        #pragma unroll
        for (int i = 0; i < 4; ++i) dst[tid + i*512] = src[tid + i*512];
    }
    for (int c = tid; c < CC; c += 512) h1l[c] = (unsigned short)h1[c];

    const int lane = tid & 63;
    const int wv   = tid >> 6;
    const int esub = wv & 3;
    const int shf  = wv >> 2;         // s-half
    const int l15  = lane & 15;
    const int l4   = lane >> 4;
    const int eg   = e0 + esub*16 + l15;

    int gh2[4];
    #pragma unroll
    for (int j = 0; j < 4; ++j) gh2[j] = h2[e0 + ((tid + j*512) >> 5)];
    __syncthreads();

    const char* Abase = (const char*)A1u + (size_t)b*NCKA*SROWS*64;

#define STAGE_A(K, BUF) { \
    const char* cbase = Abase + (size_t)(ch*NCH + (K))*SROWS*64; \
    gload16(cbase + wv*1024 + lane*16, (char*)(BUF) + wv*1024); \
    if (wv < 2) \
        gload16(cbase + 8192 + wv*1024 + lane*16, \
                (char*)(BUF) + 8192 + wv*1024); \
    }

#define GATHER(K, MT) { \
    _Pragma("unroll") \
    for (int j = 0; j < 4; ++j) { \
        int idx = tid + j*512; \
        int ge = idx >> 5, gc = idx & 31; \
        int ad = ((int)h1l[cb0 + (K)*32 + gc] + gh2[j]) & (DD-1); \
        MT[ge*M01W + gc] = ZPl[ad]; \
    } }

#define LOADB2(K) \
    (*(const short8*)&M11[((size_t)(ch*NCH + (K))*768 + eg)*32 + l4*8])

#define MFMA_STEP(LT, MT, BQ) { \
    const unsigned int* mp = &MT[(esub*16 + l15)*M01W + l4*8]; \
    uint4 p0 = *(const uint4*)mp; \
    uint4 p1 = *(const uint4*)(mp + 4); \
    union { unsigned int u[4]; short8 s; } b0, b1; \
    b0.u[0] = (p0.x & 0xffffu) | (p0.y << 16); \
    b1.u[0] = (p0.x >> 16)     | (p0.y & 0xffff0000u); \
    b0.u[1] = (p0.z & 0xffffu) | (p0.w << 16); \
    b1.u[1] = (p0.z >> 16)     | (p0.w & 0xffff0000u); \
    b0.u[2] = (p1.x & 0xffffu) | (p1.y << 16); \
    b1.u[2] = (p1.x >> 16)     | (p1.y & 0xffff0000u); \
    b0.u[3] = (p1.z & 0xffffu) | (p1.w << 16); \
    b1.u[3] = (p1.z >> 16)     | (p1.w & 0xffff0000u); \
    _Pragma("unroll") \
    for (int t = 0; t < 5; ++t) { \
        int R = shf*80 + t*16 + l15; \
        short8 af = *(const short8*)&LT[R*32 + ((l4 ^ (R & 3))*8)]; \
        acc0[t] = __builtin_amdgcn_mfma_f32_16x16x32_bf16(af, b0.s, acc0[t], 0,0,0); \
        acc1[t] = __builtin_amdgcn_mfma_f32_16x16x32_bf16(af, b1.s, acc1[t], 0,0,0); \
        acc2[t] = __builtin_amdgcn_mfma_f32_16x16x32_bf16(af, BQ,   acc2[t], 0,0,0); \
    } }

    f32x4 acc0[5], acc1[5], acc2[5];
    #pragma unroll
    for (int t = 0; t < 5; ++t) {
        acc0[t] = (f32x4){0.f,0.f,0.f,0.f};
        acc1[t] = (f32x4){0.f,0.f,0.f,0.f};
        acc2[t] = (f32x4){0.f,0.f,0.f,0.f};
    }

    short8 bqA, bqB;
    STAGE_A(0, Lt[0])
    GATHER(0, Mt01[0])
    bqA = LOADB2(0);
    __syncthreads();

    #pragma unroll 1
    for (int k = 0; k < NCH; k += 2) {
        if (k + 1 < NCH) {
            STAGE_A(k + 1, Lt[1])
            GATHER(k + 1, Mt01[1])
            bqB = LOADB2(k + 1);
        }
        MFMA_STEP(Lt[0], Mt01[0], bqA)
        __syncthreads();

        if (k + 2 < NCH) {
            STAGE_A(k + 2, Lt[0])
            GATHER(k + 2, Mt01[0])
            bqA = LOADB2(k + 2);
        }
        if (k + 1 < NCH) {
            MFMA_STEP(Lt[1], Mt01[1], bqB)
        }
        __syncthreads();
    }
#undef STAGE_A
#undef GATHER
#undef LOADB2
#undef MFMA_STEP

    // --- epilogue: combine 3 forms, reduce 16 e-lanes, one atomic ---
    const float s2e = (float)s2[eg];
    const float t2e = tok[CC + eg] * s2e;
    #pragma unroll
    for (int t = 0; t < 5; ++t) {
        #pragma unroll
        for (int rr = 0; rr < 4; ++rr) {
            int s = shf*80 + t*16 + l4*4 + rr;
            float qv = 0.f;
            if (s < SS) {
                float a2v = E[((size_t)b*SS + s)*CC + eg] * s2e + t2e;
                float w2v = Ws2[s], bbv = bs2[s];
                qv = (w2v*w2v*acc0[t][rr] + w2v*bbv*acc1[t][rr]
                      + bbv*bbv*acc2[t][rr]) * a2v;
            }
            qv += __shfl_xor(qv, 1);
            qv += __shfl_xor(qv, 2);
            qv += __shfl_xor(qv, 4);
            qv += __shfl_xor(qv, 8);
            if (l15 == 0 && s < SS)
                unsafeAtomicAdd(&Q[b*SS + s], qv);
        }
    }
}

// ---------------------------------------------------------------------------
// kE: bp = sign(Q)*sqrt(|Q|+1e-5); L2-normalize over s; project W_out.
// ---------------------------------------------------------------------------
__global__ __launch_bounds__(256) void kE(
    const float* __restrict__ Q, const float* __restrict__ Wout,
    const float* __restrict__ bout, float* __restrict__ out)
{
    __shared__ float red[8];
    const int b = blockIdx.x, tid = threadIdx.x;
    float v = 0.f, w = 0.f;
    if (tid < SS) {
        float ip = Q[b*SS + tid];
        float sg = (ip > 0.f) ? 1.f : ((ip < 0.f) ? -1.f : 0.f);
        v = sg * sqrtf(fabsf(ip) + 1e-5f);
        w = v * Wout[tid];
    }
    float sq = v * v;
    #pragma unroll
    for (int off = 32; off > 0; off >>= 1) {
        sq += __shfl_down(sq, off, 64);
        w  += __shfl_down(w,  off, 64);
    }
    if ((tid & 63) == 0) { red[tid >> 6] = sq; red[4 + (tid >> 6)] = w; }
    __syncthreads();
    if (tid == 0) {
        float ssq  = red[0] + red[1] + red[2] + red[3];
        float sw   = red[4] + red[5] + red[6] + red[7];
        float norm = fmaxf(sqrtf(ssq), 1e-12f);
        out[b] = sw / norm + bout[0];
    }
}

// ---------------------------------------------------------------------------
extern "C" void kernel_launch(void* const* d_in, const int* in_sizes, int n_in,
                              void* d_out, int out_size, void* d_ws, size_t ws_size,
                              hipStream_t stream) {
    const float* sensor = (const float*)d_in[0];
    const float* E      = (const float*)d_in[1];
    const int*   h1     = (const int*)d_in[3];
    const int*   h2     = (const int*)d_in[4];
    const int*   s1     = (const int*)d_in[5];
    const int*   s2     = (const int*)d_in[6];
    const float* Wsen   = (const float*)d_in[8];
    const float* bsen   = (const float*)d_in[9];
    const float* Ws2    = (const float*)d_in[10];
    const float* bs2    = (const float*)d_in[11];
    const float* Wout   = (const float*)d_in[12];
    const float* bout   = (const float*)d_in[13];
    const float* tok    = (const float*)d_in[14];
    float* out = (float*)d_out;

    // ws (~9.7 MB): phase1 CTG+P2G in [0,2.5M); kA's A1u overwrites [0,7.86M).
    // Non-aliased tail: ZP (1 MB) + Z11b (16 KB) + M11 (1.18 MB) + Q.
    char* ws = (char*)d_ws;
    float4* CTG = (float4*)ws;
    float2* P2G = (float2*)(ws + (size_t)BB*CC*16);
    unsigned int* A1u = (unsigned int*)ws;
    const size_t A1_BYTES = (size_t)BB*NCKA*SROWS*64;          // 7,864,320
    unsigned int*   ZP   = (unsigned int*)(ws + A1_BYTES);
    unsigned short* Z11b = (unsigned short*)(ws + A1_BYTES + (size_t)BB*DD*4);
    unsigned int*   M11u = (unsigned int*)((char*)Z11b + (size_t)DD*2);
    float* Q = (float*)((char*)M11u + (size_t)NCKA*768*32*2);

    hipMemsetAsync(Q, 0, (size_t)BB*SS*sizeof(float), stream);

    kS<<<dim3(BB), dim3(512), 0, stream>>>(
        sensor, Wsen, bsen, h1, h2, s1, s2, CTG, P2G);

    kZ<<<dim3(BB*NSL), dim3(ZT), 0, stream>>>(CTG, P2G, ZP, Z11b);

    // kA overwrites CTG/P2G (ordered after kZ on the same stream)
    kA<<<dim3(BB, SROWS/16), dim3(384), 0, stream>>>(E, tok, s1, A1u);

    kM11<<<dim3(NCKA), dim3(512), 0, stream>>>(Z11b, h1, h2, M11u);

    kD<<<dim3(NWGD), dim3(512), 0, stream>>>(
        A1u, (const unsigned short*)M11u, E, tok, h1, h2, s2, Ws2, bs2, ZP, Q);

    kE<<<dim3(BB), dim3(256), 0, stream>>>(Q, Wout, bout, out);
}